// Round 4
// baseline (100.141 us; speedup 1.0000x reference)
//
#include <hip/hip_runtime.h>
#include <math.h>

// KAN dense layer, MI355X. N_IN=N_OUT=128, K=3, G=8, BATCH=512.
// Uniform grid => closed-form cubic B-spline, 4 nonzero basis fns per x.
// v4: v2/v3 were bound by per-lane ADDRESS DIVERGENCE in the c_basis gather
//     (64 divergent addrs/instr -> ~16 lines, TA-serialized; dwordx4 repack
//     was neutral). Fix: stage each block's c_basis slice (8 o-rows, cspl
//     folded) into LDS with coalesced loads; inner gather becomes LDS reads
//     (divergence-native). Basis recomputed from t in-regs to fit 64KB LDS.
#define N_IN  128
#define N_OUT 128
#define BATCH 512
#define NK    11       // G+K coeffs per edge
#define TB    8        // batch tile
#define TO    8        // output tile
#define CBS   1412     // LDS stride per o-row (1408 + pad; %32==4 -> <=2-way banks)

__global__ __launch_bounds__(256) void kan_kernel(
    const float* __restrict__ x,       // [512][128]
    const float* __restrict__ cbasis,  // [16384][11]
    const float* __restrict__ cspl,    // [16384] flat
    const float* __restrict__ cres,    // [16384] flat
    const float* __restrict__ bias,    // [128]
    float* __restrict__ y)             // [512][128]
{
    __shared__ float  sCB[TO * CBS];      // cspl*c_basis slice   45,184 B
    __shared__ float2 sEx[TB * 130];      // (silu, base+t/2)      8,320 B
    __shared__ float  sCR[TO * 129];      // cres slice            4,128 B
    __shared__ float  sRed[256];          //                       1,024 B

    const int b0 = blockIdx.x * TB;       // 64 blocks in x
    const int o0 = blockIdx.y * TO;       // 16 blocks in y
    const int t  = threadIdx.x;

    // ---- Stage c_basis*cspl slice: fully coalesced global reads ----
    for (int o_l = 0; o_l < TO; ++o_l) {
        const int erow = (o0 + o_l) * N_IN;           // first edge of this o-row
        const float* src = cbasis + (size_t)erow * NK; // 1408 contiguous floats
        for (int p = t; p < N_IN * NK; p += 256) {
            const int i = (unsigned)p / NK;            // const-div -> mul_hi
            sCB[o_l * CBS + p] = src[p] * cspl[erow + i];
        }
    }
    // ---- Stage (silu, base+t/2) per (b,i) ----
    for (int p = t; p < TB * N_IN; p += 256) {
        const int b_l = p >> 7, i = p & 127;
        const float xv = x[(b0 + b_l) * N_IN + i];
        const float u  = (xv + 1.75f) * 4.0f;          // u in [3,11)
        float jf = floorf(u);
        jf = fminf(fmaxf(jf, 3.0f), 10.0f);
        const float tt = u - jf;
        const int base = (int)jf - 3;                  // 0..7
        const float sig  = 1.0f / (1.0f + __expf(-xv));
        sEx[b_l * 130 + i] = make_float2(xv * sig, (float)base + 0.5f * tt);
    }
    // ---- Stage cres slice ----
    for (int p = t; p < TO * N_IN; p += 256) {
        const int o_l = p >> 7, i = p & 127;
        sCR[o_l * 129 + i] = cres[(o0 + o_l) * N_IN + i];
    }
    __syncthreads();

    // ---- Phase 2: thread = (b_l, o_l, i-quarter); h is wave-uniform ----
    const int b_l = t & 7;
    const int o_l = (t >> 3) & 7;
    const int h   = t >> 6;                  // 0..3
    const int o   = o0 + o_l;
    const int i0  = h * 32;

    const float2* exBase = &sEx[b_l * 130];
    const float*  crBase = &sCR[o_l * 129];
    const float*  cbBase = &sCB[o_l * CBS];

    float acc = 0.0f;
#pragma unroll 4
    for (int ii = 0; ii < 32; ++ii) {
        const int i = i0 + ii;
        const float2 ex = exBase[i];
        const float cr  = crBase[i];
        // decompose (base + t/2)
        const float fb = truncf(ex.y);
        const int base = (int)fb;
        const float tt = (ex.y - fb) * 2.0f;
        // cubic B-spline basis from t (B0+B1+B2+B3 == 1)
        const float t2  = tt * tt;
        const float t3  = t2 * tt;
        const float omt = 1.0f - tt;
        const float B0  = omt * omt * omt * (1.0f / 6.0f);
        const float B1  = fmaf(0.5f, t3, (2.0f / 3.0f)) - t2;
        const float B3  = t3 * (1.0f / 6.0f);
        const float B2  = 1.0f - B0 - B1 - B3;
        // LDS gather: <=2-way bank alias by construction (CBS%32==4)
        const float* c = cbBase + i * NK + base;
        float spl = c[0] * B0;
        spl = fmaf(c[1], B1, spl);
        spl = fmaf(c[2], B2, spl);
        spl = fmaf(c[3], B3, spl);
        acc += spl;
        acc = fmaf(cr, ex.x, acc);
    }

    sRed[t] = acc;
    __syncthreads();
    if (h == 0) {
        const float tot = sRed[t] + sRed[t + 64] + sRed[t + 128] + sRed[t + 192]
                        + bias[o];
        y[(b0 + b_l) * N_OUT + o] = tot;
    }
}

extern "C" void kernel_launch(void* const* d_in, const int* in_sizes, int n_in,
                              void* d_out, int out_size, void* d_ws, size_t ws_size,
                              hipStream_t stream) {
    const float* x      = (const float*)d_in[0];
    // d_in[1] = knots: unused — uniform grid is known in closed form
    const float* cbasis = (const float*)d_in[2];
    const float* cspl   = (const float*)d_in[3];
    const float* cres   = (const float*)d_in[4];
    const float* bias   = (const float*)d_in[5];
    float* y = (float*)d_out;

    dim3 grid(BATCH / TB, N_OUT / TO);   // 64 x 16 = 1024 blocks
    kan_kernel<<<grid, 256, 0, stream>>>(x, cbasis, cspl, cres, bias, y);
}

// Round 5
// 71.353 us; speedup vs baseline: 1.4035x; 1.4035x over previous
//
#include <hip/hip_runtime.h>
#include <math.h>

// KAN dense layer, MI355X. N_IN=N_OUT=128, K=3, G=8, BATCH=512.
// v5: reformulate as bf16 MFMA GEMM. Densify the 4-nonzero cubic-B-spline
//     basis into K-strips of 12 per input i (11 basis slots + 1 silu slot):
//       y[b,o] = sum_k A[b,k]*W[o,k] + bias[o],  K = 128*12 = 1536
//       A[b][i*12+g] = B_g(x[b,i]) (4 nonzero),  A[b][i*12+11] = silu(x[b,i])
//       W[o][i*12+g] = cspl[o,i]*c_basis[o*128+i, g],  W[o][i*12+11] = cres[o,i]
//     Kills the 8.4M-edge gather that bound v2 (TA pipe, ~15us) and v4
//     (LDS+VALU latency, ~45us). K split into two i-halves so LDS = 54 KB.
#define N_IN  128
#define N_OUT 128
#define BATCH 512
#define NK    11
#define TBV   16    // batch tile (MFMA M)
#define TOV   16    // out tile   (MFMA N)
#define STR   776   // shorts per LDS row-half: 768 + 8 pad (1552 B, 16B-aligned;
                    // dword stride 388 %32 = 4 -> frag reads 2-way banked = free)

typedef float f32x4  __attribute__((ext_vector_type(4)));
typedef short bf16x8 __attribute__((ext_vector_type(8)));

__device__ __forceinline__ unsigned short f2bf(float f) {   // RNE fp32->bf16
    unsigned u = __float_as_uint(f);
    u += 0x7FFFu + ((u >> 16) & 1u);
    return (unsigned short)(u >> 16);
}

__global__ __launch_bounds__(256) void kan_kernel(
    const float* __restrict__ x,       // [512][128]
    const float* __restrict__ cbasis,  // [16384][11]
    const float* __restrict__ cspl,    // [16384]
    const float* __restrict__ cres,    // [16384]
    const float* __restrict__ bias,    // [128]
    float* __restrict__ y)             // [512][128]
{
    __shared__ short sA[TBV * STR];    // 24,832 B  A half-slab (bf16)
    __shared__ short sW[TOV * STR];    // 24,832 B  W half-slab (bf16)
    __shared__ float sAcc[4 * 256];    //  4,096 B  per-wave partial C tiles

    const int b0 = blockIdx.x * TBV;   // 32 blocks in x
    const int o0 = blockIdx.y * TOV;   // 8 blocks in y
    const int t  = threadIdx.x;
    const int w  = t >> 6;             // wave id: K-quarter owner
    const int l  = t & 63;
    const int mn = l & 15;             // MFMA A-row m / B-row n
    const int kq = (l >> 4) * 8;       // k-quad offset within frag

    f32x4 acc = {0.f, 0.f, 0.f, 0.f};

    for (int hh = 0; hh < 2; ++hh) {   // i-half: i in [64*hh, 64*hh+64)
        // ---- zero A half-slab (scatter only writes 5 of 12 slots) ----
        for (int p = t; p < (TBV * STR) / 8; p += 256)
            *(int4*)&sA[p * 8] = make_int4(0, 0, 0, 0);
        __syncthreads();

        // ---- build A: 16 b x 64 i pairs, 4 per thread ----
        for (int p = t; p < TBV * 64; p += 256) {
            const int b  = p >> 6, il = p & 63;
            const int i  = hh * 64 + il;
            const float xv = x[(b0 + b) * N_IN + i];        // coalesced
            const float u  = (xv + 1.75f) * 4.0f;           // u in [3,11)
            float jf = floorf(u);
            jf = fminf(fmaxf(jf, 3.0f), 10.0f);
            const float tt = u - jf;
            const float omt = 1.0f - tt;
            const float t2 = tt * tt, t3 = t2 * tt;
            const float B0 = omt * omt * omt * (1.0f / 6.0f);
            const float B1 = (3.0f * t3 - 6.0f * t2 + 4.0f) * (1.0f / 6.0f);
            const float B2 = (-3.0f * t3 + 3.0f * t2 + 3.0f * tt + 1.0f) * (1.0f / 6.0f);
            const float B3 = t3 * (1.0f / 6.0f);
            const int base = (int)jf - 3;                   // 0..7
            const float sig = 1.0f / (1.0f + __expf(-xv));
            short* dst = &sA[b * STR + il * 12];
            dst[base]     = (short)f2bf(B0);
            dst[base + 1] = (short)f2bf(B1);
            dst[base + 2] = (short)f2bf(B2);
            dst[base + 3] = (short)f2bf(B3);
            dst[11]       = (short)f2bf(xv * sig);
        }

        // ---- build W: 16 o x 64 i strips, 4 per thread ----
        for (int p = t; p < TOV * 64; p += 256) {
            const int o_l = p >> 6, il = p & 63;
            const int i   = hh * 64 + il;
            const int e   = (o0 + o_l) * N_IN + i;          // edge index
            const float s = cspl[e];
            const float* src = cbasis + (size_t)e * NK;
            unsigned short hv[12];
            #pragma unroll
            for (int g = 0; g < 11; ++g) hv[g] = f2bf(s * src[g]);
            hv[11] = f2bf(cres[e]);
            unsigned d[6];
            #pragma unroll
            for (int j = 0; j < 6; ++j)
                d[j] = (unsigned)hv[2 * j] | ((unsigned)hv[2 * j + 1] << 16);
            short* dst = &sW[o_l * STR + il * 12];          // il*24 B, 8-aligned
            *(uint2*)(dst)     = make_uint2(d[0], d[1]);
            *(uint2*)(dst + 4) = make_uint2(d[2], d[3]);
            *(uint2*)(dst + 8) = make_uint2(d[4], d[5]);
        }
        __syncthreads();

        // ---- MFMA: wave w owns k' in [192w, 192w+192): 6 steps of 32 ----
        const short* aB = &sA[mn * STR + w * 192 + kq];
        const short* bB = &sW[mn * STR + w * 192 + kq];
        #pragma unroll
        for (int s = 0; s < 6; ++s) {
            bf16x8 af  = *(const bf16x8*)(aB + s * 32);     // 16B-aligned
            bf16x8 bf_ = *(const bf16x8*)(bB + s * 32);
            acc = __builtin_amdgcn_mfma_f32_16x16x32_bf16(af, bf_, acc, 0, 0, 0);
        }
        __syncthreads();   // protect slabs from next half's zero-fill
    }

    // ---- reduce 4 wave-partials; C layout: col=lane&15, row=(lane>>4)*4+r ----
    #pragma unroll
    for (int r = 0; r < 4; ++r)
        sAcc[w * 256 + ((l >> 4) * 4 + r) * 16 + mn] = acc[r];
    __syncthreads();
    {
        const int m2 = t >> 4, n2 = t & 15;
        const float sum = sAcc[t] + sAcc[256 + t] + sAcc[512 + t] + sAcc[768 + t];
        y[(b0 + m2) * N_OUT + (o0 + n2)] = sum + bias[o0 + n2];
    }
}

extern "C" void kernel_launch(void* const* d_in, const int* in_sizes, int n_in,
                              void* d_out, int out_size, void* d_ws, size_t ws_size,
                              hipStream_t stream) {
    const float* x      = (const float*)d_in[0];
    // d_in[1] = knots: unused — uniform grid known in closed form
    const float* cbasis = (const float*)d_in[2];
    const float* cspl   = (const float*)d_in[3];
    const float* cres   = (const float*)d_in[4];
    const float* bias   = (const float*)d_in[5];
    float* y = (float*)d_out;

    dim3 grid(BATCH / TBV, N_OUT / TOV);   // 32 x 8 = 256 blocks = 1/CU
    kan_kernel<<<grid, 256, 0, stream>>>(x, cbasis, cspl, cres, bias, y);
}

// Round 6
// 69.012 us; speedup vs baseline: 1.4511x; 1.0339x over previous
//
#include <hip/hip_runtime.h>
#include <math.h>

// KAN dense layer, MI355X. N_IN=N_OUT=128, K=3, G=8, BATCH=512.
// v6: v5 profiled ~15us; dominated by per-block W re-pack (32x redundant
//     cbasis read + bf16 pack), zero-fill pass, 6 barriers. Split:
//       w_pack: W[o][k] bf16 once (k=i*12+g; 11 spline slots * cspl + cres
//               slot; silu slot pairs on the A side). 384 KB to d_ws.
//       kan:    A-slab only in LDS (branchless 192-bit shift pack, 3x
//               ds_write_b64, no zero pass); W frags prefetched to regs
//               from global before A-build; 12 MFMA/wave; v5's reduce.
#define N_IN  128
#define N_OUT 128
#define BATCH 512
#define NK    11
#define TBV   16
#define TOV   16
#define KTOT  1536           // 128 * 12
#define ASTR  1544           // shorts per A LDS row (1536 + 8 pad)

typedef float f32x4  __attribute__((ext_vector_type(4)));
typedef short bf16x8 __attribute__((ext_vector_type(8)));
typedef unsigned long long u64;

__device__ __forceinline__ unsigned short f2bf(float f) {   // RNE fp32->bf16
    unsigned u = __float_as_uint(f);
    u += 0x7FFFu + ((u >> 16) & 1u);
    return (unsigned short)(u >> 16);
}

// W[o][i*12+g] = cspl[e]*cbasis[e][g] (g<11), slot 11 = cres[e]; e = o*128+i.
// dst offset = e*12 shorts -> contiguous 24 B per thread, coalesced.
__global__ __launch_bounds__(128) void w_pack(
    const float* __restrict__ cbasis, const float* __restrict__ cspl,
    const float* __restrict__ cres, unsigned short* __restrict__ w2)
{
    const int e = blockIdx.x * 128 + threadIdx.x;    // 0..16383
    const float s = cspl[e];
    const float* src = cbasis + (size_t)e * NK;
    unsigned short h[12];
    #pragma unroll
    for (int g = 0; g < NK; ++g) h[g] = f2bf(s * src[g]);
    h[11] = f2bf(cres[e]);
    unsigned d[6];
    #pragma unroll
    for (int j = 0; j < 6; ++j)
        d[j] = (unsigned)h[2 * j] | ((unsigned)h[2 * j + 1] << 16);
    unsigned short* dst = w2 + (size_t)e * 12;
    *(uint2*)(dst)     = make_uint2(d[0], d[1]);
    *(uint2*)(dst + 4) = make_uint2(d[2], d[3]);
    *(uint2*)(dst + 8) = make_uint2(d[4], d[5]);
}

__global__ __launch_bounds__(256) void kan_kernel(
    const float* __restrict__ x,              // [512][128]
    const unsigned short* __restrict__ w2,    // [128][1536] bf16 packed
    const float* __restrict__ bias,           // [128]
    float* __restrict__ y)                    // [512][128]
{
    __shared__ short sA[TBV * ASTR];          // 49,408 B
    __shared__ float sAcc[4 * 256];           //  4,096 B

    const int b0 = blockIdx.x * TBV;          // 32 blocks in x
    const int o0 = blockIdx.y * TOV;          // 8 blocks in y
    const int t  = threadIdx.x;
    const int w  = t >> 6;                    // wave: owns K range [384w,384w+384)
    const int l  = t & 63;
    const int mn = l & 15;                    // MFMA row (m for A, n for B)
    const int kq = (l >> 4) * 8;              // k sub-offset within 32-k step

    // ---- prefetch this wave's 12 W fragments (latency hidden by A-build) ----
    const unsigned short* wb = w2 + (size_t)(o0 + mn) * KTOT + w * 384 + kq;
    bf16x8 wf[12];
    #pragma unroll
    for (int s = 0; s < 12; ++s)
        wf[s] = *(const bf16x8*)(wb + s * 32);   // global_load_dwordx4, 16B-aligned

    // ---- build A slab: 16 b x 128 i, 8 per thread, no zero pass ----
    #pragma unroll
    for (int it = 0; it < 8; ++it) {
        const int p = t + it * 256;
        const int b = p >> 7, i = p & 127;
        const float xv = x[(b0 + b) * N_IN + i];         // coalesced
        const float u  = (xv + 1.75f) * 4.0f;            // u in (3,11)
        float jf = floorf(u);
        jf = fminf(fmaxf(jf, 3.0f), 10.0f);
        const float tt = u - jf;
        const float omt = 1.0f - tt;
        const float t2 = tt * tt, t3 = t2 * tt;
        const float B0 = omt * omt * omt * (1.0f / 6.0f);
        const float B1 = (3.0f * t3 - 6.0f * t2 + 4.0f) * (1.0f / 6.0f);
        const float B2 = (-3.0f * t3 + 3.0f * t2 + 3.0f * tt + 1.0f) * (1.0f / 6.0f);
        const float B3 = t3 * (1.0f / 6.0f);
        const int base = (int)jf - 3;                    // 0..7
        const float sig = 1.0f / (1.0f + __expf(-xv));
        // pack 4 bf16 into u64, place at bit offset base*16 within 192-bit row-strip
        const u64 v4 = (u64)f2bf(B0) | ((u64)f2bf(B1) << 16)
                     | ((u64)f2bf(B2) << 32) | ((u64)f2bf(B3) << 48);
        const int sh = base * 16;                        // 0..112
        u64 q0, q1, q2;
        if (sh < 64) {
            q0 = v4 << sh;
            q1 = sh ? (v4 >> (64 - sh)) : 0ull;
            q2 = 0ull;
        } else {
            q0 = 0ull;
            q1 = v4 << (sh - 64);
            q2 = (sh > 64) ? (v4 >> (128 - sh)) : 0ull;
        }
        q2 |= (u64)f2bf(xv * sig) << 48;                 // silu -> slot 11
        u64* dst = (u64*)&sA[b * ASTR + i * 12];         // 8B-aligned
        dst[0] = q0; dst[1] = q1; dst[2] = q2;
    }
    __syncthreads();

    // ---- MFMA: 12 steps of 16x16x32 over this wave's K range ----
    f32x4 acc = {0.f, 0.f, 0.f, 0.f};
    const short* aB = &sA[mn * ASTR + w * 384 + kq];     // 16B-aligned
    #pragma unroll
    for (int s = 0; s < 12; ++s) {
        bf16x8 af = *(const bf16x8*)(aB + s * 32);       // ds_read_b128
        acc = __builtin_amdgcn_mfma_f32_16x16x32_bf16(af, wf[s], acc, 0, 0, 0);
    }

    // ---- reduce 4 wave-partials; C layout: col=lane&15, row=(lane>>4)*4+r ----
    #pragma unroll
    for (int r = 0; r < 4; ++r)
        sAcc[w * 256 + ((l >> 4) * 4 + r) * 16 + mn] = acc[r];
    __syncthreads();
    {
        const int m2 = t >> 4, n2 = t & 15;
        const float sum = sAcc[t] + sAcc[256 + t] + sAcc[512 + t] + sAcc[768 + t];
        y[(b0 + m2) * N_OUT + (o0 + n2)] = sum + bias[o0 + n2];
    }
}

extern "C" void kernel_launch(void* const* d_in, const int* in_sizes, int n_in,
                              void* d_out, int out_size, void* d_ws, size_t ws_size,
                              hipStream_t stream) {
    const float* x      = (const float*)d_in[0];
    // d_in[1] = knots: unused — uniform grid known in closed form
    const float* cbasis = (const float*)d_in[2];
    const float* cspl   = (const float*)d_in[3];
    const float* cres   = (const float*)d_in[4];
    const float* bias   = (const float*)d_in[5];
    float* y = (float*)d_out;
    unsigned short* w2 = (unsigned short*)d_ws;   // 128*1536*2 B = 384 KB scratch

    w_pack<<<128, 128, 0, stream>>>(cbasis, cspl, cres, w2);
    dim3 grid(BATCH / TBV, N_OUT / TOV);          // 32 x 8 = 256 blocks
    kan_kernel<<<grid, 256, 0, stream>>>(x, w2, bias, y);
}

// Round 7
// 66.994 us; speedup vs baseline: 1.4948x; 1.0301x over previous
//
#include <hip/hip_runtime.h>
#include <math.h>

// KAN dense layer, MI355X. N_IN=N_OUT=128, K=3, G=8, BATCH=512.
// v7: v6 ran 1 wave/SIMD (256 thr, 1 block/CU) -> A-build VALU chain and
//     cross-XCD w2 prefetch latency fully exposed. Now 512 thr = 8 waves
//     = 2 waves/SIMD; wave owns K/8=192 (6 MFMA), A-build 4 iters/thread.
//     Same two-kernel split: w_pack once (384 KB), kan reads packed W.
#define N_IN  128
#define N_OUT 128
#define BATCH 512
#define NK    11
#define TBV   16
#define TOV   16
#define KTOT  1536           // 128 * 12
#define ASTR  1544           // shorts per A LDS row (1536 + 8 pad)

typedef float f32x4  __attribute__((ext_vector_type(4)));
typedef short bf16x8 __attribute__((ext_vector_type(8)));
typedef unsigned long long u64;

__device__ __forceinline__ unsigned short f2bf(float f) {   // RNE fp32->bf16
    unsigned u = __float_as_uint(f);
    u += 0x7FFFu + ((u >> 16) & 1u);
    return (unsigned short)(u >> 16);
}

// W[o][i*12+g] = cspl[e]*cbasis[e][g] (g<11), slot 11 = cres[e]; e = o*128+i.
__global__ __launch_bounds__(128) void w_pack(
    const float* __restrict__ cbasis, const float* __restrict__ cspl,
    const float* __restrict__ cres, unsigned short* __restrict__ w2)
{
    const int e = blockIdx.x * 128 + threadIdx.x;    // 0..16383
    const float s = cspl[e];
    const float* src = cbasis + (size_t)e * NK;
    unsigned short h[12];
    #pragma unroll
    for (int g = 0; g < NK; ++g) h[g] = f2bf(s * src[g]);
    h[11] = f2bf(cres[e]);
    unsigned d[6];
    #pragma unroll
    for (int j = 0; j < 6; ++j)
        d[j] = (unsigned)h[2 * j] | ((unsigned)h[2 * j + 1] << 16);
    unsigned short* dst = w2 + (size_t)e * 12;
    *(uint2*)(dst)     = make_uint2(d[0], d[1]);
    *(uint2*)(dst + 4) = make_uint2(d[2], d[3]);
    *(uint2*)(dst + 8) = make_uint2(d[4], d[5]);
}

__global__ __launch_bounds__(512) void kan_kernel(
    const float* __restrict__ x,              // [512][128]
    const unsigned short* __restrict__ w2,    // [128][1536] bf16 packed
    const float* __restrict__ bias,           // [128]
    float* __restrict__ y)                    // [512][128]
{
    __shared__ short sA[TBV * ASTR];          // 49,408 B
    __shared__ float sAcc[8 * 256];           //  8,192 B

    const int b0 = blockIdx.x * TBV;          // 32 blocks in x
    const int o0 = blockIdx.y * TOV;          // 8 blocks in y
    const int t  = threadIdx.x;
    const int w  = t >> 6;                    // wave 0..7: owns K [192w,192w+192)
    const int l  = t & 63;
    const int mn = l & 15;                    // MFMA row (m for A, n for B)
    const int kq = (l >> 4) * 8;              // k sub-offset within 32-k step

    // ---- prefetch this wave's 6 W fragments (latency hidden by A-build) ----
    const unsigned short* wb = w2 + (size_t)(o0 + mn) * KTOT + w * 192 + kq;
    bf16x8 wf[6];
    #pragma unroll
    for (int s = 0; s < 6; ++s)
        wf[s] = *(const bf16x8*)(wb + s * 32);   // global_load_dwordx4

    // ---- build A slab: 16 b x 128 i, 4 per thread ----
    float xv[4];
    #pragma unroll
    for (int it = 0; it < 4; ++it) {          // hoist x loads: one vmcnt wait
        const int p = t + it * 512;
        xv[it] = x[(b0 + (p >> 7)) * N_IN + (p & 127)];
    }
    #pragma unroll
    for (int it = 0; it < 4; ++it) {
        const int p = t + it * 512;
        const int b = p >> 7, i = p & 127;
        const float v = xv[it];
        const float u = (v + 1.75f) * 4.0f;              // u in [3,11)
        float jf = floorf(u);
        jf = fminf(fmaxf(jf, 3.0f), 10.0f);
        const float tt = u - jf;
        const float omt = 1.0f - tt;
        const float t2 = tt * tt, t3 = t2 * tt;
        const float B0 = omt * omt * omt * (1.0f / 6.0f);
        const float B1 = (3.0f * t3 - 6.0f * t2 + 4.0f) * (1.0f / 6.0f);
        const float B2 = (-3.0f * t3 + 3.0f * t2 + 3.0f * tt + 1.0f) * (1.0f / 6.0f);
        const float B3 = t3 * (1.0f / 6.0f);
        const int base = (int)jf - 3;                    // 0..7
        const float sig = 1.0f / (1.0f + __expf(-v));
        // 4 bf16 -> u64, placed at bit offset base*16 in the 192-bit strip
        const u64 v4 = (u64)f2bf(B0) | ((u64)f2bf(B1) << 16)
                     | ((u64)f2bf(B2) << 32) | ((u64)f2bf(B3) << 48);
        const int sh = base * 16;                        // 0..112
        u64 q0, q1, q2;
        if (sh < 64) {
            q0 = v4 << sh;
            q1 = sh ? (v4 >> (64 - sh)) : 0ull;
            q2 = 0ull;
        } else {
            q0 = 0ull;
            q1 = v4 << (sh - 64);
            q2 = (sh > 64) ? (v4 >> (128 - sh)) : 0ull;
        }
        q2 |= (u64)f2bf(v * sig) << 48;                  // silu -> slot 11
        u64* dst = (u64*)&sA[b * ASTR + i * 12];         // 8B-aligned
        dst[0] = q0; dst[1] = q1; dst[2] = q2;
    }
    __syncthreads();

    // ---- MFMA: 6 steps of 16x16x32 over this wave's K range ----
    f32x4 acc = {0.f, 0.f, 0.f, 0.f};
    const short* aB = &sA[mn * ASTR + w * 192 + kq];     // 16B-aligned
    #pragma unroll
    for (int s = 0; s < 6; ++s) {
        bf16x8 af = *(const bf16x8*)(aB + s * 32);       // ds_read_b128
        acc = __builtin_amdgcn_mfma_f32_16x16x32_bf16(af, wf[s], acc, 0, 0, 0);
    }

    // ---- reduce 8 wave-partials; C layout: col=lane&15, row=(lane>>4)*4+r ----
    #pragma unroll
    for (int r = 0; r < 4; ++r)
        sAcc[w * 256 + ((l >> 4) * 4 + r) * 16 + mn] = acc[r];
    __syncthreads();
    if (t < 256) {
        const int m2 = t >> 4, n2 = t & 15;
        float sum = bias[o0 + n2];
        #pragma unroll
        for (int ww = 0; ww < 8; ++ww) sum += sAcc[ww * 256 + t];
        y[(b0 + m2) * N_OUT + (o0 + n2)] = sum;
    }
}

extern "C" void kernel_launch(void* const* d_in, const int* in_sizes, int n_in,
                              void* d_out, int out_size, void* d_ws, size_t ws_size,
                              hipStream_t stream) {
    const float* x      = (const float*)d_in[0];
    // d_in[1] = knots: unused — uniform grid known in closed form
    const float* cbasis = (const float*)d_in[2];
    const float* cspl   = (const float*)d_in[3];
    const float* cres   = (const float*)d_in[4];
    const float* bias   = (const float*)d_in[5];
    float* y = (float*)d_out;
    unsigned short* w2 = (unsigned short*)d_ws;   // 384 KB scratch

    w_pack<<<128, 128, 0, stream>>>(cbasis, cspl, cres, w2);
    dim3 grid(BATCH / TBV, N_OUT / TOV);          // 32 x 8 = 256 blocks, 1/CU
    kan_kernel<<<grid, 512, 0, stream>>>(x, w2, bias, y);
}